// Round 1
// baseline (117.129 us; speedup 1.0000x reference)
//
#include <hip/hip_runtime.h>
#include <stdint.h>

// x: [64, 512, 32, 32] f32. Pixels P = 64*1024 = 65536; channels N = 512; K = 52.
// Per pixel: exact top-K sum via bit-space binary search with wave ballot counts.

#define NCH 512
#define K_TOP 52
#define PIX_PER_BLK 16
#define NBLOCKS 4096      // 65536 / 16
#define LDS_STRIDE 516    // 512 + 4: makes stage writes/reads <=2-way bank aliasing (free)

__global__ __launch_bounds__(256, 4) void hah_select_kernel(const float* __restrict__ x,
                                                            float* __restrict__ ws) {
    __shared__ float lds[PIX_PER_BLK * LDS_STRIDE];
    __shared__ float red[4];

    const int t    = threadIdx.x;
    const int lane = t & 63;
    const int w    = t >> 6;           // wave id 0..3
    const int b    = blockIdx.x;

    // global pixel tile
    const int pix_global = b * PIX_PER_BLK;        // 16-aligned, never crosses batch (1024%16==0)
    const int batch = pix_global >> 10;
    const int pix0  = pix_global & 1023;
    const float* __restrict__ xb = x + (size_t)batch * NCH * 1024;

    // ---- stage [512][16] tile into LDS (relu applied), coalesced float4 on pixels ----
    const int n_local = t >> 2;        // 0..63
    const int p0      = (t & 3) * 4;   // 0,4,8,12
    #pragma unroll
    for (int c = 0; c < 8; ++c) {
        const int n = c * 64 + n_local;
        const float4 v = *reinterpret_cast<const float4*>(xb + (size_t)n * 1024 + pix0 + p0);
        lds[(p0 + 0) * LDS_STRIDE + n] = fmaxf(v.x, 0.0f);
        lds[(p0 + 1) * LDS_STRIDE + n] = fmaxf(v.y, 0.0f);
        lds[(p0 + 2) * LDS_STRIDE + n] = fmaxf(v.z, 0.0f);
        lds[(p0 + 3) * LDS_STRIDE + n] = fmaxf(v.w, 0.0f);
    }
    __syncthreads();

    const float C1 = (1.0f / (float)K_TOP + 1.0f / (float)(NCH - K_TOP));
    const float C2 = (1.0f / (float)(NCH - K_TOP));

    float acc = 0.0f;
    #pragma unroll 1
    for (int r = 0; r < 4; ++r) {
        const int p = r * 4 + w;       // this wave's pixel this round

        float v[8];
        #pragma unroll
        for (int j = 0; j < 8; ++j)
            v[j] = lds[p * LDS_STRIDE + j * 64 + lane];

        // total relu sum
        float s = ((v[0] + v[1]) + (v[2] + v[3])) + ((v[4] + v[5]) + (v[6] + v[7]));
        #pragma unroll
        for (int m = 32; m >= 1; m >>= 1)
            s += __shfl_xor(s, m, 64);

        uint32_t u[8];
        #pragma unroll
        for (int j = 0; j < 8; ++j)
            u[j] = __float_as_uint(v[j]);   // nonneg floats: uint order == float order

        // binary search: largest T with count(u >= T) >= K_TOP
        uint32_t lo = 0u, hi = 0x7F800000u;
        #pragma unroll 1
        for (int it = 0; it < 31; ++it) {
            const uint32_t mid = (lo + hi + 1u) >> 1;
            int cnt = 0;
            #pragma unroll
            for (int j = 0; j < 8; ++j)
                cnt += __popcll(__ballot(u[j] >= mid));
            if (cnt >= K_TOP) lo = mid; else hi = mid - 1u;
        }
        const uint32_t T = lo;
        const float Tf = __uint_as_float(T);

        // count and sum of strictly-greater values
        int cgt = 0;
        float sgt = 0.0f;
        #pragma unroll
        for (int j = 0; j < 8; ++j) {
            const bool g = (u[j] > T);
            cgt += __popcll(__ballot(g));
            sgt += g ? v[j] : 0.0f;
        }
        #pragma unroll
        for (int m = 32; m >= 1; m >>= 1)
            sgt += __shfl_xor(sgt, m, 64);

        const float top_sum = sgt + (float)(K_TOP - cgt) * Tf;  // exact incl. ties
        acc += top_sum * C1 - s * C2;
    }

    // acc is wave-uniform; combine 4 waves -> one partial per block
    if (lane == 0) red[w] = acc;
    __syncthreads();
    if (t == 0) ws[b] = (red[0] + red[1]) + (red[2] + red[3]);
}

__global__ void hah_reduce_kernel(const float* __restrict__ ws, float* __restrict__ out) {
    __shared__ float red[256];
    float s = 0.0f;
    for (int i = threadIdx.x; i < NBLOCKS; i += 256) s += ws[i];
    red[threadIdx.x] = s;
    __syncthreads();
    for (int step = 128; step >= 1; step >>= 1) {
        if (threadIdx.x < step) red[threadIdx.x] += red[threadIdx.x + step];
        __syncthreads();
    }
    if (threadIdx.x == 0) out[0] = red[0] * (1.0f / 65536.0f);
}

extern "C" void kernel_launch(void* const* d_in, const int* in_sizes, int n_in,
                              void* d_out, int out_size, void* d_ws, size_t ws_size,
                              hipStream_t stream) {
    const float* x = (const float*)d_in[0];
    float* out = (float*)d_out;
    float* ws  = (float*)d_ws;   // 4096 floats = 16 KB partials

    hah_select_kernel<<<NBLOCKS, 256, 0, stream>>>(x, ws);
    hah_reduce_kernel<<<1, 256, 0, stream>>>(ws, out);
}

// Round 3
// 112.075 us; speedup vs baseline: 1.0451x; 1.0451x over previous
//
#include <hip/hip_runtime.h>
#include <stdint.h>

// x: [64, 512, 32, 32] f32. 65536 pixels, 512 channels, K=52.
// Exact per-pixel top-K via bit-space binary search (ballot counting),
// 4 pixels interleaved per wave, popcounts split SALU/VALU.
// All loops statically bounded (graph-replay / hang safety).

#define NCH 512
#define K_TOP 52
#define PIX_PER_BLK 16
#define NBLOCKS 4096
#define LDS_STRIDE 516     // 516 mod 32 == 4: staging writes conflict-free, reads lane-consecutive

#define PROBE_LO 0x3F600000u  // 0.875f
#define PROBE_HI 0x3FE00000u  // 1.75f

__device__ __forceinline__ int count_ge(const uint32_t* u, uint32_t midv) {
    // count of the wave's 512 values >= midv (unsigned compare == float compare for relu'd data)
    uint64_t m0 = __ballot(u[0] >= midv);
    uint64_t m1 = __ballot(u[1] >= midv);
    uint64_t m2 = __ballot(u[2] >= midv);
    uint64_t m3 = __ballot(u[3] >= midv);
    uint64_t m4 = __ballot(u[4] >= midv);
    uint64_t m5 = __ballot(u[5] >= midv);
    uint64_t m6 = __ballot(u[6] >= midv);
    uint64_t m7 = __ballot(u[7] >= midv);
    // SALU half: 4 masks via s_bcnt1 (compiler picks scalar popcount for uniform values)
    int sc = (int)(__popcll(m0) + __popcll(m1) + __popcll(m2) + __popcll(m3));
    // VALU half: 4 masks via v_bcnt_u32_b32 (dst = bcnt(src0) + src1), src0 = SGPR is legal (1 SGPR read)
    uint32_t vc;
    asm("v_bcnt_u32_b32 %0, %1, 0"  : "=v"(vc) : "s"((uint32_t)m4));
    asm("v_bcnt_u32_b32 %0, %1, %2" : "=v"(vc) : "s"((uint32_t)(m4 >> 32)), "v"(vc));
    asm("v_bcnt_u32_b32 %0, %1, %2" : "=v"(vc) : "s"((uint32_t)m5),         "v"(vc));
    asm("v_bcnt_u32_b32 %0, %1, %2" : "=v"(vc) : "s"((uint32_t)(m5 >> 32)), "v"(vc));
    asm("v_bcnt_u32_b32 %0, %1, %2" : "=v"(vc) : "s"((uint32_t)m6),         "v"(vc));
    asm("v_bcnt_u32_b32 %0, %1, %2" : "=v"(vc) : "s"((uint32_t)(m6 >> 32)), "v"(vc));
    asm("v_bcnt_u32_b32 %0, %1, %2" : "=v"(vc) : "s"((uint32_t)m7),         "v"(vc));
    asm("v_bcnt_u32_b32 %0, %1, %2" : "=v"(vc) : "s"((uint32_t)(m7 >> 32)), "v"(vc));
    return sc + (int)vc;
}

__device__ __forceinline__ void bs_step(const uint32_t* u, uint32_t& lo, uint32_t& hi) {
    uint32_t midv = (lo + hi + 1u) >> 1;
    int cnt = count_ge(u, midv);
    bool ge = (cnt >= K_TOP);
    lo = ge ? midv : lo;
    hi = ge ? hi : (midv - 1u);
}

__device__ __forceinline__ void probe_step(const uint32_t* u, uint32_t& lo, uint32_t& hi,
                                           uint32_t midv) {
    // guarded fixed-threshold probe: only applies if midv is inside (lo, hi]
    int cnt = count_ge(u, midv);
    bool valid = (midv > lo) && (midv <= hi);
    bool ge = (cnt >= K_TOP);
    lo = (valid && ge)  ? midv        : lo;
    hi = (valid && !ge) ? (midv - 1u) : hi;
}

__global__ __launch_bounds__(256, 4) void hah_select_kernel(const float* __restrict__ x,
                                                            float* __restrict__ ws) {
    __shared__ float lds[PIX_PER_BLK * LDS_STRIDE];
    __shared__ float red_s[256];
    __shared__ float red_w[4];

    const int t    = threadIdx.x;
    const int lane = t & 63;
    const int w    = t >> 6;
    const int b    = blockIdx.x;

    const int pix_global = b * PIX_PER_BLK;
    const int batch = pix_global >> 10;
    const int pix0  = pix_global & 1023;
    const float* __restrict__ xb = x + (size_t)batch * NCH * 1024;

    // ---- stage [512][16] relu'd tile; accumulate per-thread relu sum ----
    const int n_local = t >> 2;
    const int p0      = (t & 3) * 4;
    float relu_acc = 0.0f;
    #pragma unroll
    for (int c = 0; c < 8; ++c) {
        const int n = c * 64 + n_local;
        const float4 v = *reinterpret_cast<const float4*>(xb + (size_t)n * 1024 + pix0 + p0);
        const float r0 = fmaxf(v.x, 0.0f), r1 = fmaxf(v.y, 0.0f);
        const float r2 = fmaxf(v.z, 0.0f), r3 = fmaxf(v.w, 0.0f);
        lds[(p0 + 0) * LDS_STRIDE + n] = r0;
        lds[(p0 + 1) * LDS_STRIDE + n] = r1;
        lds[(p0 + 2) * LDS_STRIDE + n] = r2;
        lds[(p0 + 3) * LDS_STRIDE + n] = r3;
        relu_acc += (r0 + r1) + (r2 + r3);
    }
    red_s[t] = relu_acc;
    __syncthreads();

    // ---- load this wave's 4 pixels into registers ----
    uint32_t u[4][8];
    #pragma unroll
    for (int i = 0; i < 4; ++i)
        #pragma unroll
        for (int j = 0; j < 8; ++j)
            u[i][j] = __float_as_uint(lds[(w * 4 + i) * LDS_STRIDE + j * 64 + lane]);

    // ---- interleaved binary search (4 independent chains) ----
    uint32_t lo[4], hi[4];
    #pragma unroll
    for (int i = 0; i < 4; ++i) { lo[i] = 0u; hi[i] = 0x7F800000u; }

    #pragma unroll
    for (int i = 0; i < 4; ++i) probe_step(u[i], lo[i], hi[i], PROBE_HI);
    #pragma unroll
    for (int i = 0; i < 4; ++i) probe_step(u[i], lo[i], hi[i], PROBE_LO);

    #pragma unroll 1
    for (int it = 0; it < 24; ++it) {
        #pragma unroll
        for (int i = 0; i < 4; ++i) bs_step(u[i], lo[i], hi[i]);
    }

    // mop-up: statically bounded (2 probes + 24 + 8 = 34 >= 31 worst-case bisection
    // steps over the full [0, 0x7F800000] range, so exact for ANY input).
    // Guard is wave-uniform; taken only if a pixel's threshold fell outside the
    // probe window (P ~ 1e-7 per pixel for N(0,1) data).
    if (((lo[0] ^ hi[0]) | (lo[1] ^ hi[1]) | (lo[2] ^ hi[2]) | (lo[3] ^ hi[3])) != 0u) {
        #pragma unroll 1
        for (int it = 0; it < 8; ++it) {
            #pragma unroll
            for (int i = 0; i < 4; ++i) bs_step(u[i], lo[i], hi[i]);
        }
    }

    // ---- tie-exact top-sum: sgt over all 4 pixels, one wave reduce ----
    float sgt_lane = 0.0f;
    float topc = 0.0f;   // wave-uniform
    #pragma unroll
    for (int i = 0; i < 4; ++i) {
        const uint32_t T = lo[i];
        const int cgt = count_ge(u[i], T + 1u);   // strictly-greater count (< K_TOP)
        #pragma unroll
        for (int j = 0; j < 8; ++j)
            sgt_lane += (u[i][j] > T) ? __uint_as_float(u[i][j]) : 0.0f;
        topc += (float)(K_TOP - cgt) * __uint_as_float(T);
    }
    #pragma unroll
    for (int m = 32; m >= 1; m >>= 1)
        sgt_lane += __shfl_xor(sgt_lane, m, 64);
    if (lane == 0) red_w[w] = sgt_lane + topc;
    __syncthreads();

    // ---- block combine: C1 * sum(topsum) - C2 * sum(relu) ----
    if (w == 0) {
        float s4 = red_s[lane] + red_s[lane + 64] + red_s[lane + 128] + red_s[lane + 192];
        #pragma unroll
        for (int m = 32; m >= 1; m >>= 1)
            s4 += __shfl_xor(s4, m, 64);
        if (lane == 0) {
            const float C1 = (1.0f / (float)K_TOP + 1.0f / (float)(NCH - K_TOP));
            const float C2 = (1.0f / (float)(NCH - K_TOP));
            const float top = (red_w[0] + red_w[1]) + (red_w[2] + red_w[3]);
            ws[b] = top * C1 - s4 * C2;
        }
    }
}

__global__ void hah_reduce_kernel(const float* __restrict__ ws, float* __restrict__ out) {
    __shared__ float red[256];
    float s = 0.0f;
    for (int i = threadIdx.x; i < NBLOCKS; i += 256) s += ws[i];
    red[threadIdx.x] = s;
    __syncthreads();
    for (int step = 128; step >= 1; step >>= 1) {
        if (threadIdx.x < step) red[threadIdx.x] += red[threadIdx.x + step];
        __syncthreads();
    }
    if (threadIdx.x == 0) out[0] = red[0] * (1.0f / 65536.0f);
}

extern "C" void kernel_launch(void* const* d_in, const int* in_sizes, int n_in,
                              void* d_out, int out_size, void* d_ws, size_t ws_size,
                              hipStream_t stream) {
    const float* x = (const float*)d_in[0];
    float* out = (float*)d_out;
    float* ws  = (float*)d_ws;

    hah_select_kernel<<<NBLOCKS, 256, 0, stream>>>(x, ws);
    hah_reduce_kernel<<<1, 256, 0, stream>>>(ws, out);
}

// Round 4
// 58.581 us; speedup vs baseline: 1.9994x; 1.9132x over previous
//
#include <hip/hip_runtime.h>
#include <stdint.h>

// x: [64, 512, 32, 32] f32. 65536 pixels, 512 channels, K=52.
// Per pixel: bracket the K-th value with 4 scalar-state ballot probes,
// compact <=64 candidates to LDS, 64-lane bitonic sort, exact threshold,
// then one tie-exact full-set pass. Bounded bisection fallback for any input.

#define NCH 512
#define K_TOP 52
#define PIX_PER_BLK 16
#define NBLOCKS 4096
#define LDS_STRIDE 516

#define PROBE_LO 0x3F600000u  // 0.875f
#define PROBE_HI 0x3FE00000u  // 1.75f
#define INF_BITS 0x7F800000u

// full-set count of values >= midv; everything stays scalar (SGPR) after ballot
__device__ __forceinline__ int count_ge8(const uint32_t u[8], uint32_t midv) {
    int c = 0;
    #pragma unroll
    for (int j = 0; j < 8; ++j)
        c += (int)__popcll(__ballot(u[j] >= midv));
    return c;
}

// adaptive bisection step maintaining {lo,hi,c_lo,c_top}:
//   invariant: cnt(>=lo) = c_lo >= K,  cnt(>hi) = c_top < K
__device__ __forceinline__ void bs_step(const uint32_t u[8], uint32_t& lo, uint32_t& hi,
                                        int& clo, int& ctop) {
    const uint32_t midv = (lo + hi + 1u) >> 1;
    const int cnt = count_ge8(u, midv);
    const bool ge = (cnt >= K_TOP);
    lo   = ge ? midv : lo;
    clo  = ge ? cnt  : clo;
    hi   = ge ? hi   : (midv - 1u);
    ctop = ge ? ctop : cnt;
}

// fixed-threshold probe, applied only if midv is inside (lo, hi]
__device__ __forceinline__ void probe_step(const uint32_t u[8], uint32_t& lo, uint32_t& hi,
                                           int& clo, int& ctop, uint32_t midv) {
    const int cnt = count_ge8(u, midv);
    const bool valid = (midv > lo) && (midv <= hi);
    const bool ge = valid && (cnt >= K_TOP);
    const bool lt = valid && (cnt < K_TOP);
    lo   = ge ? midv : lo;
    clo  = ge ? cnt  : clo;
    hi   = lt ? (midv - 1u) : hi;
    ctop = lt ? cnt  : ctop;
}

__global__ __launch_bounds__(256, 4) void hah_select_kernel(const float* __restrict__ x,
                                                            float* __restrict__ ws) {
    __shared__ float lds[PIX_PER_BLK * LDS_STRIDE];
    __shared__ uint32_t cand_lds[4][4][64];   // [wave][pixel][slot], wave-private
    __shared__ float red_s[256];
    __shared__ float red_w[4];

    const int t    = threadIdx.x;
    const int lane = t & 63;
    const int w    = t >> 6;
    const int b    = blockIdx.x;

    const int pix_global = b * PIX_PER_BLK;
    const int batch = pix_global >> 10;
    const int pix0  = pix_global & 1023;
    const float* __restrict__ xb = x + (size_t)batch * NCH * 1024;

    // ---- stage [512][16] relu'd tile; accumulate per-thread relu sum ----
    const int n_local = t >> 2;
    const int p0      = (t & 3) * 4;
    float relu_acc = 0.0f;
    #pragma unroll
    for (int c = 0; c < 8; ++c) {
        const int n = c * 64 + n_local;
        const float4 v = *reinterpret_cast<const float4*>(xb + (size_t)n * 1024 + pix0 + p0);
        const float r0 = fmaxf(v.x, 0.0f), r1 = fmaxf(v.y, 0.0f);
        const float r2 = fmaxf(v.z, 0.0f), r3 = fmaxf(v.w, 0.0f);
        lds[(p0 + 0) * LDS_STRIDE + n] = r0;
        lds[(p0 + 1) * LDS_STRIDE + n] = r1;
        lds[(p0 + 2) * LDS_STRIDE + n] = r2;
        lds[(p0 + 3) * LDS_STRIDE + n] = r3;
        relu_acc += (r0 + r1) + (r2 + r3);
    }
    red_s[t] = relu_acc;
    __syncthreads();

    // ---- this wave's 4 pixels into registers ----
    uint32_t u[4][8];
    #pragma unroll
    for (int i = 0; i < 4; ++i)
        #pragma unroll
        for (int j = 0; j < 8; ++j)
            u[i][j] = __float_as_uint(lds[(w * 4 + i) * LDS_STRIDE + j * 64 + lane]);

    // ---- bracket: 2 fixed probes + 2 adaptive bisections (scalar state) ----
    uint32_t lo[4], hi[4];
    int clo[4], ctop[4];
    #pragma unroll
    for (int i = 0; i < 4; ++i) { lo[i] = 0u; hi[i] = INF_BITS; clo[i] = NCH; ctop[i] = 0; }

    #pragma unroll
    for (int i = 0; i < 4; ++i) probe_step(u[i], lo[i], hi[i], clo[i], ctop[i], PROBE_HI);
    #pragma unroll
    for (int i = 0; i < 4; ++i) probe_step(u[i], lo[i], hi[i], clo[i], ctop[i], PROBE_LO);
    #pragma unroll
    for (int i = 0; i < 4; ++i) bs_step(u[i], lo[i], hi[i], clo[i], ctop[i]);
    #pragma unroll
    for (int i = 0; i < 4; ++i) bs_step(u[i], lo[i], hi[i], clo[i], ctop[i]);

    // ---- compact candidates (values in [lo,hi]) to cand_lds, zero-padded ----
    #pragma unroll
    for (int i = 0; i < 4; ++i) cand_lds[w][i][lane] = 0u;   // pads (< any midv >= lo+1)

    bool all_fast = true;
    int rank[4];
    #pragma unroll
    for (int i = 0; i < 4; ++i) {
        const int m = clo[i] - ctop[i];          // candidate count
        rank[i] = K_TOP - ctop[i];               // 1-based rank inside candidates
        all_fast = all_fast && (m <= 64);
        int base = 0;
        #pragma unroll
        for (int j = 0; j < 8; ++j) {
            const bool pred = (u[i][j] >= lo[i]) && (u[i][j] <= hi[i]);
            const uint64_t mk = __ballot(pred);
            const int pre = __builtin_amdgcn_mbcnt_hi((uint32_t)(mk >> 32),
                             __builtin_amdgcn_mbcnt_lo((uint32_t)mk, 0u));
            const int slot = base + pre;
            if (pred && slot < 64) cand_lds[w][i][slot] = u[i][j];
            base += (int)__popcll(mk);
        }
    }

    uint32_t T[4];
    if (all_fast) {
        // ---- 64-lane bitonic sort (descending), 4 pixels interleaved ----
        uint32_t cand[4];
        #pragma unroll
        for (int i = 0; i < 4; ++i) cand[i] = cand_lds[w][i][lane];
        #pragma unroll
        for (int k = 2; k <= 64; k <<= 1) {
            #pragma unroll
            for (int j = k >> 1; j >= 1; j >>= 1) {
                const bool takeMax = ((lane & k) == 0) == ((lane & j) == 0);
                #pragma unroll
                for (int i = 0; i < 4; ++i) {
                    const uint32_t o = (uint32_t)__shfl_xor((int)cand[i], j, 64);
                    const uint32_t mx = cand[i] > o ? cand[i] : o;
                    const uint32_t mn = cand[i] > o ? o : cand[i];
                    cand[i] = takeMax ? mx : mn;
                }
            }
        }
        // threshold = rank-th largest candidate = exact 52nd largest overall
        #pragma unroll
        for (int i = 0; i < 4; ++i)
            T[i] = (uint32_t)__shfl((int)cand[i], rank[i] - 1, 64);
    } else {
        // bounded exact fallback: 31 more bisection steps converge from any state
        #pragma unroll 1
        for (int it = 0; it < 31; ++it) {
            #pragma unroll
            for (int i = 0; i < 4; ++i) bs_step(u[i], lo[i], hi[i], clo[i], ctop[i]);
        }
        #pragma unroll
        for (int i = 0; i < 4; ++i) T[i] = lo[i];
    }

    // ---- tie-exact final pass over the full set ----
    float sgt_lane = 0.0f;
    float topc = 0.0f;   // wave-uniform
    #pragma unroll
    for (int i = 0; i < 4; ++i) {
        const int cgt = count_ge8(u[i], T[i] + 1u);   // strictly-greater count (< K)
        #pragma unroll
        for (int j = 0; j < 8; ++j)
            sgt_lane += (u[i][j] > T[i]) ? __uint_as_float(u[i][j]) : 0.0f;
        topc += (float)(K_TOP - cgt) * __uint_as_float(T[i]);
    }
    #pragma unroll
    for (int m = 32; m >= 1; m >>= 1)
        sgt_lane += __shfl_xor(sgt_lane, m, 64);
    if (lane == 0) red_w[w] = sgt_lane + topc;
    __syncthreads();

    // ---- block combine: C1 * sum(topsum) - C2 * sum(relu) ----
    if (w == 0) {
        float s4 = red_s[lane] + red_s[lane + 64] + red_s[lane + 128] + red_s[lane + 192];
        #pragma unroll
        for (int m = 32; m >= 1; m >>= 1)
            s4 += __shfl_xor(s4, m, 64);
        if (lane == 0) {
            const float C1 = (1.0f / (float)K_TOP + 1.0f / (float)(NCH - K_TOP));
            const float C2 = (1.0f / (float)(NCH - K_TOP));
            const float top = (red_w[0] + red_w[1]) + (red_w[2] + red_w[3]);
            ws[b] = top * C1 - s4 * C2;
        }
    }
}

__global__ void hah_reduce_kernel(const float* __restrict__ ws, float* __restrict__ out) {
    __shared__ float red[256];
    float s = 0.0f;
    for (int i = threadIdx.x; i < NBLOCKS; i += 256) s += ws[i];
    red[threadIdx.x] = s;
    __syncthreads();
    for (int step = 128; step >= 1; step >>= 1) {
        if (threadIdx.x < step) red[threadIdx.x] += red[threadIdx.x + step];
        __syncthreads();
    }
    if (threadIdx.x == 0) out[0] = red[0] * (1.0f / 65536.0f);
}

extern "C" void kernel_launch(void* const* d_in, const int* in_sizes, int n_in,
                              void* d_out, int out_size, void* d_ws, size_t ws_size,
                              hipStream_t stream) {
    const float* x = (const float*)d_in[0];
    float* out = (float*)d_out;
    float* ws  = (float*)d_ws;

    hah_select_kernel<<<NBLOCKS, 256, 0, stream>>>(x, ws);
    hah_reduce_kernel<<<1, 256, 0, stream>>>(ws, out);
}

// Round 5
// 57.921 us; speedup vs baseline: 2.0222x; 1.0114x over previous
//
#include <hip/hip_runtime.h>
#include <stdint.h>

// x: [64, 512, 32, 32] f32. 65536 pixels, 512 channels, K=52.
// Per pixel: early compaction to the >=0.75 candidate set (3 regs/lane),
// 2 fixed + 2 adaptive ballot probes bracket the K-th value, <=32 survivors
// sorted by a dual-pixel 32-lane bitonic, tie-exact top-sum from the compact
// set. Wave-uniform bounded bisection fallbacks keep it exact for ANY input.

#define NCH 512
#define K_TOP 52
#define PIX_PER_BLK 16
#define NBLOCKS 4096
#define LDS_STRIDE 516

#define LO_BITS   0x3F400000u  // 0.75f
#define P175_BITS 0x3FE00000u  // 1.75f
#define P125_BITS 0x3FA00000u  // 1.25f
#define INF_BITS  0x7F800000u
#define CAP_C0    192          // 3 regs * 64 lanes

static __device__ __forceinline__ int mbcnt64(uint64_t m) {
    return (int)__builtin_amdgcn_mbcnt_hi((uint32_t)(m >> 32),
            __builtin_amdgcn_mbcnt_lo((uint32_t)m, 0u));
}

__device__ __forceinline__ int count_ge8(const uint32_t u[8], uint32_t midv) {
    int c = 0;
    #pragma unroll
    for (int j = 0; j < 8; ++j)
        c += (int)__popcll(__ballot(u[j] >= midv));
    return c;
}
__device__ __forceinline__ int count_ge3(const uint32_t c3[3], uint32_t midv) {
    int c = 0;
    #pragma unroll
    for (int j = 0; j < 3; ++j)
        c += (int)__popcll(__ballot(c3[j] >= midv));
    return c;
}
__device__ __forceinline__ void bs_step8(const uint32_t u[8], uint32_t& lo, uint32_t& hi,
                                         int& clo, int& ctop) {
    const uint32_t midv = (lo + hi + 1u) >> 1;
    const int cnt = count_ge8(u, midv);
    const bool ge = (cnt >= K_TOP);
    lo = ge ? midv : lo;        clo  = ge ? cnt  : clo;
    hi = ge ? hi : (midv - 1u); ctop = ge ? ctop : cnt;
}
__device__ __forceinline__ void bs_step3(const uint32_t c3[3], uint32_t& lo, uint32_t& hi,
                                         int& clo, int& ctop) {
    const uint32_t midv = (lo + hi + 1u) >> 1;
    const int cnt = count_ge3(c3, midv);
    const bool ge = (cnt >= K_TOP);
    lo = ge ? midv : lo;        clo  = ge ? cnt  : clo;
    hi = ge ? hi : (midv - 1u); ctop = ge ? ctop : cnt;
}
__device__ __forceinline__ void probe3(const uint32_t c3[3], uint32_t& lo, uint32_t& hi,
                                       int& clo, int& ctop, uint32_t midv) {
    const int cnt = count_ge3(c3, midv);
    const bool valid = (midv > lo) && (midv <= hi);
    const bool ge = valid && (cnt >= K_TOP);
    const bool lt = valid && (cnt < K_TOP);
    lo = ge ? midv : lo;        clo  = ge ? cnt : clo;
    hi = lt ? (midv - 1u) : hi; ctop = lt ? cnt : ctop;
}

__global__ __launch_bounds__(256, 4) void hah_select_kernel(const float* __restrict__ x,
                                                            float* __restrict__ ws) {
    __shared__ float lds[PIX_PER_BLK * LDS_STRIDE];
    __shared__ float red_s[256];
    __shared__ float red_w[4];
    uint32_t* const ldsu = (uint32_t*)lds;

    const int t    = threadIdx.x;
    const int lane = t & 63;
    const int w    = t >> 6;
    const int b    = blockIdx.x;

    const int pix_global = b * PIX_PER_BLK;
    const int batch = pix_global >> 10;
    const int pix0  = pix_global & 1023;
    const float* __restrict__ xb = x + (size_t)batch * NCH * 1024;

    // ---- stage [512][16] relu'd tile; accumulate per-thread relu sum ----
    const int n_local = t >> 2;
    const int p0      = (t & 3) * 4;
    float relu_acc = 0.0f;
    #pragma unroll
    for (int c = 0; c < 8; ++c) {
        const int n = c * 64 + n_local;
        const float4 v = *reinterpret_cast<const float4*>(xb + (size_t)n * 1024 + pix0 + p0);
        const float r0 = fmaxf(v.x, 0.0f), r1 = fmaxf(v.y, 0.0f);
        const float r2 = fmaxf(v.z, 0.0f), r3 = fmaxf(v.w, 0.0f);
        lds[(p0 + 0) * LDS_STRIDE + n] = r0;
        lds[(p0 + 1) * LDS_STRIDE + n] = r1;
        lds[(p0 + 2) * LDS_STRIDE + n] = r2;
        lds[(p0 + 3) * LDS_STRIDE + n] = r3;
        relu_acc += (r0 + r1) + (r2 + r3);
    }
    red_s[t] = relu_acc;
    __syncthreads();

    // ---- this wave's 4 pixels into registers ----
    const int row = w * 4;
    uint32_t u[4][8];
    #pragma unroll
    for (int i = 0; i < 4; ++i)
        #pragma unroll
        for (int j = 0; j < 8; ++j)
            u[i][j] = __float_as_uint(lds[(row + i) * LDS_STRIDE + j * 64 + lane]);

    int c0[4];
    #pragma unroll
    for (int i = 0; i < 4; ++i) c0[i] = count_ge8(u[i], LO_BITS);

    const bool wavefast =
        (c0[0] >= K_TOP) && (c0[0] <= CAP_C0) && (c0[1] >= K_TOP) && (c0[1] <= CAP_C0) &&
        (c0[2] >= K_TOP) && (c0[2] <= CAP_C0) && (c0[3] >= K_TOP) && (c0[3] <= CAP_C0);

    float sgt_lane = 0.0f;
    float topc = 0.0f;   // wave-uniform

    if (!wavefast) {
        // ---- exact fallback: full 31-step bisection on the 8-reg set ----
        uint32_t lo[4], hi[4]; int clo[4], ctop[4];
        #pragma unroll
        for (int i = 0; i < 4; ++i) { lo[i] = 0u; hi[i] = INF_BITS; clo[i] = NCH; ctop[i] = 0; }
        #pragma unroll 1
        for (int it = 0; it < 31; ++it) {
            #pragma unroll
            for (int i = 0; i < 4; ++i) bs_step8(u[i], lo[i], hi[i], clo[i], ctop[i]);
        }
        #pragma unroll
        for (int i = 0; i < 4; ++i) {
            const uint32_t T = lo[i];
            const int cgt = count_ge8(u[i], T + 1u);
            #pragma unroll
            for (int j = 0; j < 8; ++j)
                sgt_lane += (u[i][j] > T) ? __uint_as_float(u[i][j]) : 0.0f;
            topc += (float)(K_TOP - cgt) * __uint_as_float(T);
        }
    } else {
        // ---- early compact: values >= 0.75 into this wave's own (dead) LDS rows ----
        #pragma unroll
        for (int i = 0; i < 4; ++i)
            #pragma unroll
            for (int r = 0; r < 3; ++r)
                ldsu[(row + i) * LDS_STRIDE + r * 64 + lane] = 0u;
        #pragma unroll
        for (int i = 0; i < 4; ++i) {
            int base = 0;
            #pragma unroll
            for (int j = 0; j < 8; ++j) {
                const bool pred = (u[i][j] >= LO_BITS);
                const uint64_t mk = __ballot(pred);
                const int pre = mbcnt64(mk);
                if (pred) ldsu[(row + i) * LDS_STRIDE + base + pre] = u[i][j];
                base += (int)__popcll(mk);
            }
        }
        uint32_t c3[4][3];
        #pragma unroll
        for (int i = 0; i < 4; ++i)
            #pragma unroll
            for (int r = 0; r < 3; ++r)
                c3[i][r] = ldsu[(row + i) * LDS_STRIDE + r * 64 + lane];

        // ---- bracket on the compact set: 2 fixed probes + 2 adaptive ----
        uint32_t lo[4], hi[4]; int clo[4], ctop[4];
        #pragma unroll
        for (int i = 0; i < 4; ++i) { lo[i] = LO_BITS; hi[i] = INF_BITS; clo[i] = c0[i]; ctop[i] = 0; }
        #pragma unroll
        for (int i = 0; i < 4; ++i) probe3(c3[i], lo[i], hi[i], clo[i], ctop[i], P175_BITS);
        #pragma unroll
        for (int i = 0; i < 4; ++i) probe3(c3[i], lo[i], hi[i], clo[i], ctop[i], P125_BITS);
        #pragma unroll
        for (int i = 0; i < 4; ++i) bs_step3(c3[i], lo[i], hi[i], clo[i], ctop[i]);
        #pragma unroll
        for (int i = 0; i < 4; ++i) bs_step3(c3[i], lo[i], hi[i], clo[i], ctop[i]);

        const bool wavesmall =
            (clo[0] - ctop[0] <= 32) && (clo[1] - ctop[1] <= 32) &&
            (clo[2] - ctop[2] <= 32) && (clo[3] - ctop[3] <= 32);

        uint32_t T[4]; int cgt[4];
        if (!wavesmall) {
            // bounded exact fallback on the compact set
            #pragma unroll 1
            for (int it = 0; it < 31; ++it) {
                #pragma unroll
                for (int i = 0; i < 4; ++i) bs_step3(c3[i], lo[i], hi[i], clo[i], ctop[i]);
            }
            #pragma unroll
            for (int i = 0; i < 4; ++i) { T[i] = lo[i]; cgt[i] = count_ge3(c3[i], lo[i] + 1u); }
        } else {
            // ---- window compact (<=32) then dual-pixel 32-lane bitonic ----
            #pragma unroll
            for (int i = 0; i < 4; ++i)
                ldsu[(row + i) * LDS_STRIDE + 256 + (lane & 31)] = 0u;
            #pragma unroll
            for (int i = 0; i < 4; ++i) {
                int base = 0;
                #pragma unroll
                for (int r = 0; r < 3; ++r) {
                    const bool pred = (c3[i][r] >= lo[i]) && (c3[i][r] <= hi[i]);
                    const uint64_t mk = __ballot(pred);
                    const int pre = mbcnt64(mk);
                    if (pred) ldsu[(row + i) * LDS_STRIDE + 256 + base + pre] = c3[i][r];
                    base += (int)__popcll(mk);
                }
            }
            uint32_t a  = ldsu[(row + (lane >> 5)) * LDS_STRIDE + 256 + (lane & 31)];
            uint32_t bv = ldsu[(row + 2 + (lane >> 5)) * LDS_STRIDE + 256 + (lane & 31)];
            const int l = lane & 31;
            #pragma unroll
            for (int k = 2; k <= 32; k <<= 1) {
                #pragma unroll
                for (int j = k >> 1; j >= 1; j >>= 1) {
                    const bool takeMax = ((l & k) == 0) == ((l & j) == 0);
                    {
                        const uint32_t o = (uint32_t)__shfl_xor((int)a, j, 64);
                        const uint32_t mx = a > o ? a : o, mn = a > o ? o : a;
                        a = takeMax ? mx : mn;
                    }
                    {
                        const uint32_t o = (uint32_t)__shfl_xor((int)bv, j, 64);
                        const uint32_t mx = bv > o ? bv : o, mn = bv > o ? o : bv;
                        bv = takeMax ? mx : mn;
                    }
                }
            }
            T[0] = (uint32_t)__shfl((int)a,       K_TOP - ctop[0] - 1, 64);
            T[1] = (uint32_t)__shfl((int)a,  32 + K_TOP - ctop[1] - 1, 64);
            T[2] = (uint32_t)__shfl((int)bv,      K_TOP - ctop[2] - 1, 64);
            T[3] = (uint32_t)__shfl((int)bv, 32 + K_TOP - ctop[3] - 1, 64);
            const uint32_t tA = (lane & 32) ? T[1] : T[0];
            const uint32_t tB = (lane & 32) ? T[3] : T[2];
            const uint64_t mA = __ballot(a > tA);
            const uint64_t mB = __ballot(bv > tB);
            cgt[0] = ctop[0] + (int)__builtin_popcount((uint32_t)mA);
            cgt[1] = ctop[1] + (int)__builtin_popcount((uint32_t)(mA >> 32));
            cgt[2] = ctop[2] + (int)__builtin_popcount((uint32_t)mB);
            cgt[3] = ctop[3] + (int)__builtin_popcount((uint32_t)(mB >> 32));
        }

        // ---- tie-exact top-sum from the compact set (all v > T are >= 0.75) ----
        #pragma unroll
        for (int i = 0; i < 4; ++i) {
            #pragma unroll
            for (int r = 0; r < 3; ++r)
                sgt_lane += (c3[i][r] > T[i]) ? __uint_as_float(c3[i][r]) : 0.0f;
            topc += (float)(K_TOP - cgt[i]) * __uint_as_float(T[i]);
        }
    }

    #pragma unroll
    for (int m = 32; m >= 1; m >>= 1)
        sgt_lane += __shfl_xor(sgt_lane, m, 64);
    if (lane == 0) red_w[w] = sgt_lane + topc;
    __syncthreads();

    // ---- block combine: C1 * sum(topsum) - C2 * sum(relu) ----
    if (w == 0) {
        float s4 = red_s[lane] + red_s[lane + 64] + red_s[lane + 128] + red_s[lane + 192];
        #pragma unroll
        for (int m = 32; m >= 1; m >>= 1)
            s4 += __shfl_xor(s4, m, 64);
        if (lane == 0) {
            const float C1 = (1.0f / (float)K_TOP + 1.0f / (float)(NCH - K_TOP));
            const float C2 = (1.0f / (float)(NCH - K_TOP));
            const float top = (red_w[0] + red_w[1]) + (red_w[2] + red_w[3]);
            ws[b] = top * C1 - s4 * C2;
        }
    }
}

__global__ void hah_reduce_kernel(const float* __restrict__ ws, float* __restrict__ out) {
    __shared__ float red[256];
    float s = 0.0f;
    for (int i = threadIdx.x; i < NBLOCKS; i += 256) s += ws[i];
    red[threadIdx.x] = s;
    __syncthreads();
    for (int step = 128; step >= 1; step >>= 1) {
        if (threadIdx.x < step) red[threadIdx.x] += red[threadIdx.x + step];
        __syncthreads();
    }
    if (threadIdx.x == 0) out[0] = red[0] * (1.0f / 65536.0f);
}

extern "C" void kernel_launch(void* const* d_in, const int* in_sizes, int n_in,
                              void* d_out, int out_size, void* d_ws, size_t ws_size,
                              hipStream_t stream) {
    const float* x = (const float*)d_in[0];
    float* out = (float*)d_out;
    float* ws  = (float*)d_ws;

    hah_select_kernel<<<NBLOCKS, 256, 0, stream>>>(x, ws);
    hah_reduce_kernel<<<1, 256, 0, stream>>>(ws, out);
}

// Round 6
// 40.918 us; speedup vs baseline: 2.8625x; 1.4155x over previous
//
#include <hip/hip_runtime.h>
#include <stdint.h>

// x: [64, 512, 32, 32] f32. 65536 pixels, 512 channels, K=52.
// 512-thread blocks (100% occupancy), loads-first staging (4 float4 in flight),
// XCD-chunked block swizzle. Selection: early compact to >=0.75 set (3 regs),
// 2 fixed + 2 adaptive ballot probes, dual-pixel 32-lane bitonic on <=32
// survivors, tie-exact top-sum. Bounded wave-uniform fallbacks => exact always.

#define NCH 512
#define K_TOP 52
#define PIX_PER_BLK 16
#define NBLOCKS 4096
#define LDS_STRIDE 516

#define LO_BITS   0x3F400000u  // 0.75f
#define P175_BITS 0x3FE00000u  // 1.75f
#define P125_BITS 0x3FA00000u  // 1.25f
#define INF_BITS  0x7F800000u
#define CAP_C0    192          // 3 regs * 64 lanes

static __device__ __forceinline__ int mbcnt64(uint64_t m) {
    return (int)__builtin_amdgcn_mbcnt_hi((uint32_t)(m >> 32),
            __builtin_amdgcn_mbcnt_lo((uint32_t)m, 0u));
}

__device__ __forceinline__ int count_ge8(const uint32_t u[8], uint32_t midv) {
    int c = 0;
    #pragma unroll
    for (int j = 0; j < 8; ++j)
        c += (int)__popcll(__ballot(u[j] >= midv));
    return c;
}
__device__ __forceinline__ int count_ge3(const uint32_t c3[3], uint32_t midv) {
    int c = 0;
    #pragma unroll
    for (int j = 0; j < 3; ++j)
        c += (int)__popcll(__ballot(c3[j] >= midv));
    return c;
}
__device__ __forceinline__ void bs_step8(const uint32_t u[8], uint32_t& lo, uint32_t& hi,
                                         int& clo, int& ctop) {
    const uint32_t midv = (lo + hi + 1u) >> 1;
    const int cnt = count_ge8(u, midv);
    const bool ge = (cnt >= K_TOP);
    lo = ge ? midv : lo;        clo  = ge ? cnt  : clo;
    hi = ge ? hi : (midv - 1u); ctop = ge ? ctop : cnt;
}
__device__ __forceinline__ void bs_step3(const uint32_t c3[3], uint32_t& lo, uint32_t& hi,
                                         int& clo, int& ctop) {
    const uint32_t midv = (lo + hi + 1u) >> 1;
    const int cnt = count_ge3(c3, midv);
    const bool ge = (cnt >= K_TOP);
    lo = ge ? midv : lo;        clo  = ge ? cnt  : clo;
    hi = ge ? hi : (midv - 1u); ctop = ge ? ctop : cnt;
}
__device__ __forceinline__ void probe3(const uint32_t c3[3], uint32_t& lo, uint32_t& hi,
                                       int& clo, int& ctop, uint32_t midv) {
    const int cnt = count_ge3(c3, midv);
    const bool valid = (midv > lo) && (midv <= hi);
    const bool ge = valid && (cnt >= K_TOP);
    const bool lt = valid && (cnt < K_TOP);
    lo = ge ? midv : lo;        clo  = ge ? cnt : clo;
    hi = lt ? (midv - 1u) : hi; ctop = lt ? cnt : ctop;
}

__global__ __launch_bounds__(512, 8) void hah_select_kernel(const float* __restrict__ x,
                                                            float* __restrict__ ws) {
    __shared__ float lds[PIX_PER_BLK * LDS_STRIDE];   // 33 KB
    __shared__ float red_s[512];
    __shared__ float red_w[8];
    uint32_t* const ldsu = (uint32_t*)lds;

    const int t    = threadIdx.x;
    const int lane = t & 63;
    const int w    = t >> 6;                 // wave 0..7
    // bijective XCD-chunked swizzle (NBLOCKS % 8 == 0): same-XCD blocks are
    // contiguous in pixel space -> 128B-line sharing lands in one L2
    const int bid = blockIdx.x;
    const int b   = (bid & 7) * (NBLOCKS >> 3) + (bid >> 3);

    const int pix_global = b * PIX_PER_BLK;
    const int batch = pix_global >> 10;
    const int pix0  = pix_global & 1023;
    const float* __restrict__ xb = x + (size_t)batch * NCH * 1024;

    // ---- stage [512ch][16px] relu'd tile: ALL loads issued before any write ----
    const int n_local = t >> 2;              // 0..127
    const int p0      = (t & 3) * 4;         // 0,4,8,12
    float4 vv[4];
    #pragma unroll
    for (int c = 0; c < 4; ++c)
        vv[c] = *reinterpret_cast<const float4*>(xb + (size_t)(c * 128 + n_local) * 1024 + pix0 + p0);
    float relu_acc = 0.0f;
    #pragma unroll
    for (int c = 0; c < 4; ++c) {
        const int n = c * 128 + n_local;
        const float r0 = fmaxf(vv[c].x, 0.0f), r1 = fmaxf(vv[c].y, 0.0f);
        const float r2 = fmaxf(vv[c].z, 0.0f), r3 = fmaxf(vv[c].w, 0.0f);
        lds[(p0 + 0) * LDS_STRIDE + n] = r0;
        lds[(p0 + 1) * LDS_STRIDE + n] = r1;
        lds[(p0 + 2) * LDS_STRIDE + n] = r2;
        lds[(p0 + 3) * LDS_STRIDE + n] = r3;
        relu_acc += (r0 + r1) + (r2 + r3);
    }
    red_s[t] = relu_acc;
    __syncthreads();

    // ---- this wave's 2 pixels into registers ----
    const int row = w * 2;
    uint32_t u[2][8];
    #pragma unroll
    for (int i = 0; i < 2; ++i)
        #pragma unroll
        for (int j = 0; j < 8; ++j)
            u[i][j] = __float_as_uint(lds[(row + i) * LDS_STRIDE + j * 64 + lane]);

    int c0[2];
    #pragma unroll
    for (int i = 0; i < 2; ++i) c0[i] = count_ge8(u[i], LO_BITS);

    const bool wavefast =
        (c0[0] >= K_TOP) && (c0[0] <= CAP_C0) && (c0[1] >= K_TOP) && (c0[1] <= CAP_C0);

    float sgt_lane = 0.0f;
    float topc = 0.0f;   // wave-uniform

    if (!wavefast) {
        // ---- exact fallback: full 31-step bisection on the 8-reg set ----
        uint32_t lo[2], hi[2]; int clo[2], ctop[2];
        #pragma unroll
        for (int i = 0; i < 2; ++i) { lo[i] = 0u; hi[i] = INF_BITS; clo[i] = NCH; ctop[i] = 0; }
        #pragma unroll 1
        for (int it = 0; it < 31; ++it) {
            #pragma unroll
            for (int i = 0; i < 2; ++i) bs_step8(u[i], lo[i], hi[i], clo[i], ctop[i]);
        }
        #pragma unroll
        for (int i = 0; i < 2; ++i) {
            const uint32_t T = lo[i];
            const int cgt = count_ge8(u[i], T + 1u);
            #pragma unroll
            for (int j = 0; j < 8; ++j)
                sgt_lane += (u[i][j] > T) ? __uint_as_float(u[i][j]) : 0.0f;
            topc += (float)(K_TOP - cgt) * __uint_as_float(T);
        }
    } else {
        // ---- early compact: values >= 0.75 into this wave's own (dead) LDS rows ----
        #pragma unroll
        for (int i = 0; i < 2; ++i)
            #pragma unroll
            for (int r = 0; r < 3; ++r)
                ldsu[(row + i) * LDS_STRIDE + r * 64 + lane] = 0u;
        #pragma unroll
        for (int i = 0; i < 2; ++i) {
            int base = 0;
            #pragma unroll
            for (int j = 0; j < 8; ++j) {
                const bool pred = (u[i][j] >= LO_BITS);
                const uint64_t mk = __ballot(pred);
                const int pre = mbcnt64(mk);
                if (pred) ldsu[(row + i) * LDS_STRIDE + base + pre] = u[i][j];
                base += (int)__popcll(mk);
            }
        }
        uint32_t c3[2][3];
        #pragma unroll
        for (int i = 0; i < 2; ++i)
            #pragma unroll
            for (int r = 0; r < 3; ++r)
                c3[i][r] = ldsu[(row + i) * LDS_STRIDE + r * 64 + lane];

        // ---- bracket on the compact set: 2 fixed probes + 2 adaptive ----
        uint32_t lo[2], hi[2]; int clo[2], ctop[2];
        #pragma unroll
        for (int i = 0; i < 2; ++i) { lo[i] = LO_BITS; hi[i] = INF_BITS; clo[i] = c0[i]; ctop[i] = 0; }
        #pragma unroll
        for (int i = 0; i < 2; ++i) probe3(c3[i], lo[i], hi[i], clo[i], ctop[i], P175_BITS);
        #pragma unroll
        for (int i = 0; i < 2; ++i) probe3(c3[i], lo[i], hi[i], clo[i], ctop[i], P125_BITS);
        #pragma unroll
        for (int i = 0; i < 2; ++i) bs_step3(c3[i], lo[i], hi[i], clo[i], ctop[i]);
        #pragma unroll
        for (int i = 0; i < 2; ++i) bs_step3(c3[i], lo[i], hi[i], clo[i], ctop[i]);

        const bool wavesmall = (clo[0] - ctop[0] <= 32) && (clo[1] - ctop[1] <= 32);

        uint32_t T[2]; int cgt[2];
        if (!wavesmall) {
            // bounded exact fallback on the compact set
            #pragma unroll 1
            for (int it = 0; it < 31; ++it) {
                #pragma unroll
                for (int i = 0; i < 2; ++i) bs_step3(c3[i], lo[i], hi[i], clo[i], ctop[i]);
            }
            #pragma unroll
            for (int i = 0; i < 2; ++i) { T[i] = lo[i]; cgt[i] = count_ge3(c3[i], lo[i] + 1u); }
        } else {
            // ---- window compact (<=32) then dual-pixel 32-lane bitonic ----
            #pragma unroll
            for (int i = 0; i < 2; ++i)
                ldsu[(row + i) * LDS_STRIDE + 256 + (lane & 31)] = 0u;
            #pragma unroll
            for (int i = 0; i < 2; ++i) {
                int base = 0;
                #pragma unroll
                for (int r = 0; r < 3; ++r) {
                    const bool pred = (c3[i][r] >= lo[i]) && (c3[i][r] <= hi[i]);
                    const uint64_t mk = __ballot(pred);
                    const int pre = mbcnt64(mk);
                    if (pred) ldsu[(row + i) * LDS_STRIDE + 256 + base + pre] = c3[i][r];
                    base += (int)__popcll(mk);
                }
            }
            // px0 candidates -> lanes 0..31, px1 -> lanes 32..63
            uint32_t a = ldsu[(row + (lane >> 5)) * LDS_STRIDE + 256 + (lane & 31)];
            const int l = lane & 31;
            #pragma unroll
            for (int k = 2; k <= 32; k <<= 1) {
                #pragma unroll
                for (int j = k >> 1; j >= 1; j >>= 1) {
                    const bool takeMax = ((l & k) == 0) == ((l & j) == 0);
                    const uint32_t o = (uint32_t)__shfl_xor((int)a, j, 64);
                    const uint32_t mx = a > o ? a : o, mn = a > o ? o : a;
                    a = takeMax ? mx : mn;
                }
            }
            T[0] = (uint32_t)__shfl((int)a,      K_TOP - ctop[0] - 1, 64);
            T[1] = (uint32_t)__shfl((int)a, 32 + K_TOP - ctop[1] - 1, 64);
            const uint32_t tSel = (lane & 32) ? T[1] : T[0];
            const uint64_t mA = __ballot(a > tSel);
            cgt[0] = ctop[0] + (int)__builtin_popcount((uint32_t)mA);
            cgt[1] = ctop[1] + (int)__builtin_popcount((uint32_t)(mA >> 32));
        }

        // ---- tie-exact top-sum from the compact set (all v > T are >= 0.75) ----
        #pragma unroll
        for (int i = 0; i < 2; ++i) {
            #pragma unroll
            for (int r = 0; r < 3; ++r)
                sgt_lane += (c3[i][r] > T[i]) ? __uint_as_float(c3[i][r]) : 0.0f;
            topc += (float)(K_TOP - cgt[i]) * __uint_as_float(T[i]);
        }
    }

    #pragma unroll
    for (int m = 32; m >= 1; m >>= 1)
        sgt_lane += __shfl_xor(sgt_lane, m, 64);
    if (lane == 0) red_w[w] = sgt_lane + topc;
    __syncthreads();

    // ---- block combine: C1 * sum(topsum) - C2 * sum(relu) ----
    if (w == 0) {
        float s4 = 0.0f;
        #pragma unroll
        for (int k = 0; k < 8; ++k) s4 += red_s[lane + 64 * k];
        #pragma unroll
        for (int m = 32; m >= 1; m >>= 1)
            s4 += __shfl_xor(s4, m, 64);
        if (lane == 0) {
            const float C1 = (1.0f / (float)K_TOP + 1.0f / (float)(NCH - K_TOP));
            const float C2 = (1.0f / (float)(NCH - K_TOP));
            float top = 0.0f;
            #pragma unroll
            for (int k = 0; k < 8; ++k) top += red_w[k];
            ws[b] = top * C1 - s4 * C2;
        }
    }
}

__global__ void hah_reduce_kernel(const float* __restrict__ ws, float* __restrict__ out) {
    __shared__ float red[256];
    float s = 0.0f;
    for (int i = threadIdx.x; i < NBLOCKS; i += 256) s += ws[i];
    red[threadIdx.x] = s;
    __syncthreads();
    for (int step = 128; step >= 1; step >>= 1) {
        if (threadIdx.x < step) red[threadIdx.x] += red[threadIdx.x + step];
        __syncthreads();
    }
    if (threadIdx.x == 0) out[0] = red[0] * (1.0f / 65536.0f);
}

extern "C" void kernel_launch(void* const* d_in, const int* in_sizes, int n_in,
                              void* d_out, int out_size, void* d_ws, size_t ws_size,
                              hipStream_t stream) {
    const float* x = (const float*)d_in[0];
    float* out = (float*)d_out;
    float* ws  = (float*)d_ws;

    hah_select_kernel<<<NBLOCKS, 512, 0, stream>>>(x, ws);
    hah_reduce_kernel<<<1, 256, 0, stream>>>(ws, out);
}